// Round 9
// baseline (392.736 us; speedup 1.0000x reference)
//
#include <hip/hip_runtime.h>
#include <math.h>

#define FEAT 128
#define BSHIFT 6            // 64 nodes per COARSE bucket == one GEMM tile
#define BNODES 64
#define CAP2 2048           // records per LDS sort chunk in K2 (16 KB)
#define NBUCK_MAX 1024      // N <= 65536 -> nbuck <= 1024 (fits 10 bits)
#define EPB 4096            // edges per scatter chunk: 367 blocks at E=1.5M

__device__ __forceinline__ float edge_weight(float d, float scale, float fw, float fb) {
    // scale already includes +1e-6
    float t = fmaxf(d / scale, 0.0f);
    float decay = expf(-t * t);
    float g = 1.0f / (1.0f + expf(-(d * fw + fb)));
    float w = decay * g;
    if (!isfinite(w)) w = 0.0f;
    return w;
}

__device__ __forceinline__ unsigned int bf16_rne(float f) {
    unsigned int b = __float_as_uint(f);
    return (b + 0x7FFFu + ((b >> 16) & 1u)) >> 16;
}

__device__ __forceinline__ void accum8(float acc[8], uint4 u, float w) {
    acc[0] = fmaf(w, __uint_as_float(u.x << 16), acc[0]);
    acc[1] = fmaf(w, __uint_as_float(u.x & 0xFFFF0000u), acc[1]);
    acc[2] = fmaf(w, __uint_as_float(u.y << 16), acc[2]);
    acc[3] = fmaf(w, __uint_as_float(u.y & 0xFFFF0000u), acc[3]);
    acc[4] = fmaf(w, __uint_as_float(u.z << 16), acc[4]);
    acc[5] = fmaf(w, __uint_as_float(u.z & 0xFFFF0000u), acc[5]);
    acc[6] = fmaf(w, __uint_as_float(u.w << 16), acc[6]);
    acc[7] = fmaf(w, __uint_as_float(u.w & 0xFFFF0000u), acc[7]);
}

// ==== K1: scatter chunks [0,nchunk) + convert blocks [nchunk,...).
// Scatter: LDS histogram -> LDS scan -> ONE global atomicAdd per bucket
// (reserve run) -> counting-sort records into LDS -> COALESCED writeout.
// Bucket id (10 bits) stashed in record bits 22..31 for the writeout.
__global__ __launch_bounds__(256) void convert_scatter_kernel(
    const float4* __restrict__ x4, uint2* __restrict__ xbf, int n4,
    const int* __restrict__ sender, const int* __restrict__ recv,
    const float* __restrict__ edge_len,
    const float* __restrict__ log_scale, const float* __restrict__ filter_w,
    const float* __restrict__ filter_b,
    int* __restrict__ gcnt, unsigned long long* __restrict__ buf,
    int E, int nbuck, int cap, int nchunk) {
    __shared__ unsigned long long recS[EPB];   // 32 KB
    __shared__ int cnt[NBUCK_MAX];             // histogram
    __shared__ int segoff[NBUCK_MAX];          // local exclusive scan
    __shared__ int segcur[NBUCK_MAX];          // rank cursor
    __shared__ int resbase[NBUCK_MAX];         // global run base (abs position)
    __shared__ int part[256];
    const int tid = threadIdx.x;

    if ((int)blockIdx.x >= nchunk) {            // ---- convert part ----
        int i = ((int)blockIdx.x - nchunk) * 256 + tid;
        if (i >= n4) return;
        float4 v = x4[i];
        uint2 o;
        o.x = (bf16_rne(v.y) << 16) | bf16_rne(v.x);
        o.y = (bf16_rne(v.w) << 16) | bf16_rne(v.z);
        xbf[i] = o;
        return;
    }

    // ---- scatter part ----
    const int c = blockIdx.x;
    for (int i = tid; i < nbuck; i += 256) cnt[i] = 0;
    __syncthreads();
    const int base = c * EPB;
    const int end = min(base + EPB, E);
    const int cntE = end - base;
    for (int e = base + tid; e < end; e += 256)
        atomicAdd(&cnt[recv[e] >> BSHIFT], 1);
    __syncthreads();

    // local exclusive scan over nbuck (<=1024) entries: 4 per thread
    {
        int i0 = tid * 4;
        int v0 = 0, v1 = 0, v2 = 0, v3 = 0;
        if (i0 < nbuck) {
            v0 = cnt[i0];
            v1 = (i0 + 1 < nbuck) ? cnt[i0 + 1] : 0;
            v2 = (i0 + 2 < nbuck) ? cnt[i0 + 2] : 0;
            v3 = (i0 + 3 < nbuck) ? cnt[i0 + 3] : 0;
        }
        int s = v0 + v1 + v2 + v3;
        part[tid] = s;
        __syncthreads();
        for (int d = 1; d < 256; d <<= 1) {
            int t = (tid >= d) ? part[tid - d] : 0;
            __syncthreads();
            part[tid] += t;
            __syncthreads();
        }
        int run = part[tid] - s;
        if (i0 < nbuck) {
            segoff[i0] = run; run += v0;
            if (i0 + 1 < nbuck) { segoff[i0 + 1] = run; run += v1; }
            if (i0 + 2 < nbuck) { segoff[i0 + 2] = run; run += v2; }
            if (i0 + 3 < nbuck) { segoff[i0 + 3] = run; run += v3; }
        }
    }
    // reserve global runs + init cursors
    for (int i = tid; i < nbuck; i += 256) {
        int cc = cnt[i];
        int b0 = cc ? atomicAdd(&gcnt[i], cc) : 0;
        resbase[i] = i * cap + b0;
        segcur[i] = segoff[i];
    }
    __syncthreads();

    // build records sorted-by-bucket in LDS
    float scale = expf(log_scale[0]) + 1e-6f;
    float fw = filter_w[0], fb = filter_b[0];
    for (int e = base + tid; e < end; e += 256) {
        int r = recv[e];
        int s = sender[e];
        float w = edge_weight(edge_len[e], scale, fw, fb);
        int bk = r >> BSHIFT;
        int j = atomicAdd(&segcur[bk], 1);
        recS[j] = ((unsigned long long)__float_as_uint(w) << 32)
                | (unsigned int)(s & 0xFFFF)
                | ((unsigned int)(r & (BNODES - 1)) << 16)
                | ((unsigned int)(bk & 1023) << 22);
    }
    __syncthreads();

    // coalesced writeout: sorted slot j -> run position
    for (int j = tid; j < cntE; j += 256) {
        unsigned long long rec = recS[j];
        int bk = ((unsigned int)rec >> 22) & 1023;
        int pos = resbase[bk] + (j - segoff[bk]);
        if (pos < (bk + 1) * cap)   // safety only; cap >= mean+5sigma
            buf[pos] = rec;
    }
}

// ==== K2: sort + aggregate + FUSED 64-node GEMM tile (1:1 with bucket).
// Gather phase = R8-proven single-pass. Then acc*invd staged into a [64][129]
// f32 LDS tile (union with recS; 33 KB still allows 4 blocks/CU) and the
// block computes out = x + aggS @ W for ITS OWN 64 nodes. Deletes the
// finalize dispatch, the agg_bf 25.4 MB round-trip, and deg.
__global__ __launch_bounds__(512) void sort_aggregate_finalize_kernel(
    const uint4* __restrict__ xbf4, const unsigned long long* __restrict__ buf,
    const int* __restrict__ gcnt, const float* __restrict__ x,
    const float* __restrict__ Wm, float* __restrict__ out, int N, int cap) {
    __shared__ union {
        unsigned long long recS[CAP2];      // 16 KB (gather phase)
        float aggS[BNODES * 129];           // 33 KB (GEMM phase), padded
    } S;
    __shared__ int cnt64[BNODES];
    __shared__ int segoff[BNODES + 1];

    const int b = blockIdx.x;
    const int n0 = b << BSHIFT;
    const int tid = threadIdx.x;
    const int lane = tid & 15;
    const int grp = tid >> 4;   // 0..31
    const int lo = b * cap;
    const int hi = lo + min(gcnt[b], cap);

    float acc[2][8] = {{0.f,0.f,0.f,0.f,0.f,0.f,0.f,0.f},
                       {0.f,0.f,0.f,0.f,0.f,0.f,0.f,0.f}};
    int dcnt[2] = {0, 0};

    for (int pos = lo; pos < hi; pos += CAP2) {
        int cnt = min(CAP2, hi - pos);
        if (tid < BNODES) cnt64[tid] = 0;
        __syncthreads();

        unsigned long long rec[CAP2 / 512];
        int rnk[CAP2 / 512];
        int locl[CAP2 / 512];
#pragma unroll
        for (int k = 0; k < CAP2 / 512; ++k) {
            int i = k * 512 + tid;
            rnk[k] = -1;
            if (i < cnt) {
                unsigned long long r = buf[pos + i];
                int l = ((unsigned int)r >> 16) & (BNODES - 1);
                rec[k] = r;
                locl[k] = l;
                rnk[k] = atomicAdd(&cnt64[l], 1);
            }
        }
        __syncthreads();
        if (tid == 0) {
            int run = 0;
#pragma unroll
            for (int l = 0; l < BNODES; ++l) { segoff[l] = run; run += cnt64[l]; }
            segoff[BNODES] = run;
        }
        __syncthreads();
#pragma unroll
        for (int k = 0; k < CAP2 / 512; ++k)
            if (rnk[k] >= 0) S.recS[segoff[locl[k]] + rnk[k]] = rec[k];
        __syncthreads();

#pragma unroll
        for (int which = 0; which < 2; ++which) {
            int l = grp + which * 32;
            int s0 = segoff[l], s1 = segoff[l + 1];
            dcnt[which] += s1 - s0;
            int i = s0;
            for (; i + 4 <= s1; i += 4) {
                unsigned long long r0 = S.recS[i];
                unsigned long long r1 = S.recS[i + 1];
                unsigned long long r2 = S.recS[i + 2];
                unsigned long long r3 = S.recS[i + 3];
                float w0 = __uint_as_float((unsigned int)(r0 >> 32));
                float w1 = __uint_as_float((unsigned int)(r1 >> 32));
                float w2 = __uint_as_float((unsigned int)(r2 >> 32));
                float w3 = __uint_as_float((unsigned int)(r3 >> 32));
                int s0i = (unsigned int)r0 & 0xFFFF;
                int s1i = (unsigned int)r1 & 0xFFFF;
                int s2i = (unsigned int)r2 & 0xFFFF;
                int s3i = (unsigned int)r3 & 0xFFFF;
                uint4 u0 = xbf4[(size_t)s0i * 16 + lane];
                uint4 u1 = xbf4[(size_t)s1i * 16 + lane];
                uint4 u2 = xbf4[(size_t)s2i * 16 + lane];
                uint4 u3 = xbf4[(size_t)s3i * 16 + lane];
                accum8(acc[which], u0, w0);
                accum8(acc[which], u1, w1);
                accum8(acc[which], u2, w2);
                accum8(acc[which], u3, w3);
            }
            for (; i < s1; ++i) {
                unsigned long long ra = S.recS[i];
                float wa = __uint_as_float((unsigned int)(ra >> 32));
                int sa = (unsigned int)ra & 0xFFFF;
                uint4 ua = xbf4[(size_t)sa * 16 + lane];
                accum8(acc[which], ua, wa);
            }
        }
        __syncthreads();   // all reads of recS done before reuse/next chunk
    }

    // ---- stage normalized accumulators into the [64][129] tile ------------
#pragma unroll
    for (int which = 0; which < 2; ++which) {
        int l = grp + which * 32;
        float invd = 1.0f / fmaxf((float)dcnt[which], 1.0f);
#pragma unroll
        for (int k = 0; k < 8; ++k)
            S.aggS[l * 129 + lane * 8 + k] = acc[which][k] * invd;
    }
    __syncthreads();

    // ---- fused GEMM: out[n0+r][:] = x[n0+r][:] + aggS[r][:] @ W ------------
    // thread -> (row r = tid>>3, j-group jg = tid&7 -> 16 output columns)
    {
        const int r = tid >> 3;
        const int jg = tid & 7;
        const float4* W4 = (const float4*)Wm;   // row-major 128x128 f32
        float o[16];
#pragma unroll
        for (int i = 0; i < 16; ++i) o[i] = 0.f;
#pragma unroll 4
        for (int k = 0; k < FEAT; ++k) {
            float a = S.aggS[r * 129 + k];
            float4 w0 = W4[k * 32 + jg * 4 + 0];
            float4 w1 = W4[k * 32 + jg * 4 + 1];
            float4 w2 = W4[k * 32 + jg * 4 + 2];
            float4 w3 = W4[k * 32 + jg * 4 + 3];
            o[0]  = fmaf(a, w0.x, o[0]);
            o[1]  = fmaf(a, w0.y, o[1]);
            o[2]  = fmaf(a, w0.z, o[2]);
            o[3]  = fmaf(a, w0.w, o[3]);
            o[4]  = fmaf(a, w1.x, o[4]);
            o[5]  = fmaf(a, w1.y, o[5]);
            o[6]  = fmaf(a, w1.z, o[6]);
            o[7]  = fmaf(a, w1.w, o[7]);
            o[8]  = fmaf(a, w2.x, o[8]);
            o[9]  = fmaf(a, w2.y, o[9]);
            o[10] = fmaf(a, w2.z, o[10]);
            o[11] = fmaf(a, w2.w, o[11]);
            o[12] = fmaf(a, w3.x, o[12]);
            o[13] = fmaf(a, w3.y, o[13]);
            o[14] = fmaf(a, w3.z, o[14]);
            o[15] = fmaf(a, w3.w, o[15]);
        }
        int n = n0 + r;
        if (n < N) {
            size_t basei = (size_t)n * FEAT + jg * 16;
            float4 x0 = *(const float4*)&x[basei];
            float4 x1 = *(const float4*)&x[basei + 4];
            float4 x2 = *(const float4*)&x[basei + 8];
            float4 x3 = *(const float4*)&x[basei + 12];
            float4 r0 = make_float4(x0.x + o[0],  x0.y + o[1],
                                    x0.z + o[2],  x0.w + o[3]);
            float4 r1 = make_float4(x1.x + o[4],  x1.y + o[5],
                                    x1.z + o[6],  x1.w + o[7]);
            float4 r2 = make_float4(x2.x + o[8],  x2.y + o[9],
                                    x2.z + o[10], x2.w + o[11]);
            float4 r3 = make_float4(x3.x + o[12], x3.y + o[13],
                                    x3.z + o[14], x3.w + o[15]);
            *(float4*)&out[basei]      = r0;
            *(float4*)&out[basei + 4]  = r1;
            *(float4*)&out[basei + 8]  = r2;
            *(float4*)&out[basei + 12] = r3;
        }
    }
}

// ---------------- fallback (atomic path) ---------------
__global__ __launch_bounds__(256) void scatter_fallback(
    const float4* __restrict__ x4, const int* __restrict__ sender,
    const int* __restrict__ receiver, const float* __restrict__ edge_len,
    const float* __restrict__ log_scale, const float* __restrict__ filter_w,
    const float* __restrict__ filter_b, float* __restrict__ agg,
    float* __restrict__ deg, int E) {
    int gid = blockIdx.x * 256 + threadIdx.x;
    int e = gid >> 5;
    if (e >= E) return;
    int lane = gid & 31;
    int s = sender[e];
    int r = receiver[e];
    float scale = expf(log_scale[0]) + 1e-6f;
    float w = edge_weight(edge_len[e], scale, filter_w[0], filter_b[0]);
    float4 xv = x4[s * (FEAT / 4) + lane];
    float* dst = agg + (size_t)r * FEAT + lane * 4;
    unsafeAtomicAdd(dst + 0, w * xv.x);
    unsafeAtomicAdd(dst + 1, w * xv.y);
    unsafeAtomicAdd(dst + 2, w * xv.z);
    unsafeAtomicAdd(dst + 3, w * xv.w);
    if (lane == 0) unsafeAtomicAdd(&deg[r], 1.0f);
}

__global__ __launch_bounds__(256) void finalize_fallback(
    const float* __restrict__ x, const float* __restrict__ agg,
    const float* __restrict__ deg, const float* __restrict__ Wm,
    float* __restrict__ out, int N) {
    __shared__ float Wsf[FEAT * FEAT];
    for (int i = threadIdx.x * 4; i < FEAT * FEAT; i += 256 * 4)
        *(float4*)&Wsf[i] = *(const float4*)&Wm[i];
    __syncthreads();
    int half = threadIdx.x >> 7;
    int j = threadIdx.x & (FEAT - 1);
    for (int n0 = blockIdx.x * 2; n0 < N; n0 += gridDim.x * 2) {
        int n = n0 + half;
        if (n < N) {
            const float* arow = agg + (size_t)n * FEAT;
            float acc = 0.0f;
#pragma unroll 16
            for (int k = 0; k < FEAT; ++k) acc = fmaf(arow[k], Wsf[k * FEAT + j], acc);
            float invd = 1.0f / fmaxf(deg[n], 1.0f);
            size_t idx = (size_t)n * FEAT + j;
            out[idx] = x[idx] + invd * acc;
        }
    }
}

extern "C" void kernel_launch(void* const* d_in, const int* in_sizes, int n_in,
                              void* d_out, int out_size, void* d_ws, size_t ws_size,
                              hipStream_t stream) {
    const float* x         = (const float*)d_in[0];
    const int*   ei        = (const int*)d_in[1];
    const float* edge_len  = (const float*)d_in[2];
    const float* W_mix     = (const float*)d_in[3];
    const float* log_scale = (const float*)d_in[4];
    const float* filter_w  = (const float*)d_in[5];
    const float* filter_b  = (const float*)d_in[6];
    float* out = (float*)d_out;

    const int N = in_sizes[0] / FEAT;
    const int E = in_sizes[1] / 2;
    const int* sender   = ei;
    const int* receiver = ei + E;
    const int nbuck = (N + BNODES - 1) >> BSHIFT;
    const int nchunk = (E + EPB - 1) / EPB;

    size_t xbf_bytes  = (size_t)N * FEAT * 2;
    size_t gcnt_bytes = (((size_t)nbuck * 4) + 63) & ~(size_t)63;

    // bucket region capacity: want 2*mean+512; shrink to fit; floor mean+5sigma
    int mean = E / nbuck + 1;
    size_t head = xbf_bytes + gcnt_bytes;
    size_t avail = (ws_size > head) ? ws_size - head : 0;
    int cap = (2 * mean + 512 + 63) & ~63;
    int capmax = (int)((avail / ((size_t)nbuck * 8)) & ~(size_t)63);
    if (cap > capmax) cap = capmax;
    int sigma5 = 5 * (int)sqrtf((float)mean) + 64;
    bool ok = (N <= 65536) && (nbuck <= NBUCK_MAX) && (cap >= mean + sigma5);

    if (ok) {
        char* p = (char*)d_ws;
        uint2* xbf = (uint2*)p;                           p += xbf_bytes;
        int* gcnt  = (int*)p;                             p += gcnt_bytes;
        unsigned long long* buf = (unsigned long long*)p;

        (void)hipMemsetAsync(gcnt, 0, (size_t)nbuck * sizeof(int), stream);

        int n4 = N * (FEAT / 4);
        int cblocks = (n4 + 255) / 256;
        convert_scatter_kernel<<<nchunk + cblocks, 256, 0, stream>>>(
            (const float4*)x, xbf, n4, sender, receiver, edge_len,
            log_scale, filter_w, filter_b, gcnt, buf, E, nbuck, cap, nchunk);
        sort_aggregate_finalize_kernel<<<nbuck, 512, 0, stream>>>(
            (const uint4*)xbf, buf, gcnt, x, W_mix, out, N, cap);
    } else {
        float* agg = (float*)d_ws;
        float* degf = agg + (size_t)N * FEAT;
        (void)hipMemsetAsync(agg, 0, ((size_t)N * FEAT + N) * sizeof(float), stream);
        int sblocks = (E * 32 + 255) / 256;
        scatter_fallback<<<sblocks, 256, 0, stream>>>(
            (const float4*)x, sender, receiver, edge_len,
            log_scale, filter_w, filter_b, agg, degf, E);
        finalize_fallback<<<512, 256, 0, stream>>>(x, agg, degf, W_mix, out, N);
    }
}

// Round 10
// 211.971 us; speedup vs baseline: 1.8528x; 1.8528x over previous
//
#include <hip/hip_runtime.h>
#include <math.h>

#define FEAT 128
#define BSHIFT 6            // 64 nodes per COARSE bucket
#define BNODES 64
#define CAP2 2048           // records per LDS sort chunk in K2 (16 KB)
#define NBUCK_MAX 1024      // N <= 65536 -> nbuck <= 1024 (fits 10 bits)
#define EPB 4096            // edges per scatter chunk: 367 blocks at E=1.5M
#define K1T 512             // K1 threads: 8 waves/block -> 24 waves/CU at 3 blk

__device__ __forceinline__ float edge_weight(float d, float scale, float fw, float fb) {
    // scale already includes +1e-6
    float t = fmaxf(d / scale, 0.0f);
    float decay = expf(-t * t);
    float g = 1.0f / (1.0f + expf(-(d * fw + fb)));
    float w = decay * g;
    if (!isfinite(w)) w = 0.0f;
    return w;
}

__device__ __forceinline__ unsigned int bf16_rne(float f) {
    unsigned int b = __float_as_uint(f);
    return (b + 0x7FFFu + ((b >> 16) & 1u)) >> 16;
}

__device__ __forceinline__ void accum8(float acc[8], uint4 u, float w) {
    acc[0] = fmaf(w, __uint_as_float(u.x << 16), acc[0]);
    acc[1] = fmaf(w, __uint_as_float(u.x & 0xFFFF0000u), acc[1]);
    acc[2] = fmaf(w, __uint_as_float(u.y << 16), acc[2]);
    acc[3] = fmaf(w, __uint_as_float(u.y & 0xFFFF0000u), acc[3]);
    acc[4] = fmaf(w, __uint_as_float(u.z << 16), acc[4]);
    acc[5] = fmaf(w, __uint_as_float(u.z & 0xFFFF0000u), acc[5]);
    acc[6] = fmaf(w, __uint_as_float(u.w << 16), acc[6]);
    acc[7] = fmaf(w, __uint_as_float(u.w & 0xFFFF0000u), acc[7]);
}

// ==== K1: scatter chunks [0,nchunk) + convert blocks [nchunk,...). 512 thr.
// Scatter: LDS histogram -> LDS scan -> ONE global atomicAdd per bucket
// (reserve run) -> counting-sort records into LDS -> COALESCED writeout.
// Bucket id (10 bits) stashed in record bits 22..31 for the writeout.
__global__ __launch_bounds__(K1T) void convert_scatter_kernel(
    const float4* __restrict__ x4, uint2* __restrict__ xbf, int n4,
    const int* __restrict__ sender, const int* __restrict__ recv,
    const float* __restrict__ edge_len,
    const float* __restrict__ log_scale, const float* __restrict__ filter_w,
    const float* __restrict__ filter_b,
    int* __restrict__ gcnt, unsigned long long* __restrict__ buf,
    int E, int nbuck, int cap, int nchunk) {
    __shared__ unsigned long long recS[EPB];   // 32 KB
    __shared__ int cnt[NBUCK_MAX];             // histogram, then rank cursor
    __shared__ int segoff[NBUCK_MAX];          // local exclusive scan
    __shared__ int resbase[NBUCK_MAX];         // global run base (abs position)
    __shared__ int part[K1T];
    const int tid = threadIdx.x;

    if ((int)blockIdx.x >= nchunk) {            // ---- convert part ----
        int i = ((int)blockIdx.x - nchunk) * K1T + tid;
        if (i >= n4) return;
        float4 v = x4[i];
        uint2 o;
        o.x = (bf16_rne(v.y) << 16) | bf16_rne(v.x);
        o.y = (bf16_rne(v.w) << 16) | bf16_rne(v.z);
        xbf[i] = o;
        return;
    }

    // ---- scatter part ----
    const int c = blockIdx.x;
    for (int i = tid; i < nbuck; i += K1T) cnt[i] = 0;
    __syncthreads();
    const int base = c * EPB;
    const int end = min(base + EPB, E);
    const int cntE = end - base;
    for (int e = base + tid; e < end; e += K1T)
        atomicAdd(&cnt[recv[e] >> BSHIFT], 1);
    __syncthreads();

    // local exclusive scan over nbuck (<=1024) entries: 2 per thread
    {
        int i0 = tid * 2;
        int v0 = 0, v1 = 0;
        if (i0 < nbuck) {
            v0 = cnt[i0];
            v1 = (i0 + 1 < nbuck) ? cnt[i0 + 1] : 0;
        }
        int s = v0 + v1;
        part[tid] = s;
        __syncthreads();
        for (int d = 1; d < K1T; d <<= 1) {
            int t = (tid >= d) ? part[tid - d] : 0;
            __syncthreads();
            part[tid] += t;
            __syncthreads();
        }
        int run = part[tid] - s;
        if (i0 < nbuck) {
            segoff[i0] = run; run += v0;
            if (i0 + 1 < nbuck) segoff[i0 + 1] = run;
        }
    }
    __syncthreads();
    // reserve global runs + init rank cursors (cnt becomes the cursor)
    for (int i = tid; i < nbuck; i += K1T) {
        int cc = cnt[i];
        int b0 = cc ? atomicAdd(&gcnt[i], cc) : 0;
        resbase[i] = i * cap + b0;
        cnt[i] = segoff[i];
    }
    __syncthreads();

    // build records sorted-by-bucket in LDS
    float scale = expf(log_scale[0]) + 1e-6f;
    float fw = filter_w[0], fb = filter_b[0];
    for (int e = base + tid; e < end; e += K1T) {
        int r = recv[e];
        int s = sender[e];
        float w = edge_weight(edge_len[e], scale, fw, fb);
        int bk = r >> BSHIFT;
        int j = atomicAdd(&cnt[bk], 1);
        recS[j] = ((unsigned long long)__float_as_uint(w) << 32)
                | (unsigned int)(s & 0xFFFF)
                | ((unsigned int)(r & (BNODES - 1)) << 16)
                | ((unsigned int)(bk & 1023) << 22);
    }
    __syncthreads();

    // coalesced writeout: sorted slot j -> run position
    for (int j = tid; j < cntE; j += K1T) {
        unsigned long long rec = recS[j];
        int bk = ((unsigned int)rec >> 22) & 1023;
        int pos = resbase[bk] + (j - segoff[bk]);
        if (pos < (bk + 1) * cap)   // safety only; cap >= mean+5sigma
            buf[pos] = rec;
    }
}

// ==== K2: single-pass sort+aggregate (R8-proven). One 512-thread block per
// coarse bucket; 32 groups x 2 nodes. Each record read+ranked ONCE.
__global__ __launch_bounds__(512) void bucket_sort_aggregate_kernel(
    const uint4* __restrict__ xbf4, const unsigned long long* __restrict__ buf,
    const int* __restrict__ gcnt, uint4* __restrict__ agg_bf4,
    int* __restrict__ deg, int N, int cap) {
    __shared__ unsigned long long recS[CAP2];   // 16 KB
    __shared__ int cnt64[BNODES];
    __shared__ int segoff[BNODES + 1];

    const int b = blockIdx.x;
    const int n0 = b << BSHIFT;
    const int tid = threadIdx.x;
    const int lane = tid & 15;
    const int grp = tid >> 4;   // 0..31
    const int lo = b * cap;
    const int hi = lo + min(gcnt[b], cap);

    float acc[2][8] = {{0.f,0.f,0.f,0.f,0.f,0.f,0.f,0.f},
                       {0.f,0.f,0.f,0.f,0.f,0.f,0.f,0.f}};
    int dcnt[2] = {0, 0};

    for (int pos = lo; pos < hi; pos += CAP2) {
        int cnt = min(CAP2, hi - pos);
        if (tid < BNODES) cnt64[tid] = 0;
        __syncthreads();

        unsigned long long rec[CAP2 / 512];
        int rnk[CAP2 / 512];
        int locl[CAP2 / 512];
#pragma unroll
        for (int k = 0; k < CAP2 / 512; ++k) {
            int i = k * 512 + tid;
            rnk[k] = -1;
            if (i < cnt) {
                unsigned long long r = buf[pos + i];
                int l = ((unsigned int)r >> 16) & (BNODES - 1);
                rec[k] = r;
                locl[k] = l;
                rnk[k] = atomicAdd(&cnt64[l], 1);
            }
        }
        __syncthreads();
        if (tid == 0) {
            int run = 0;
#pragma unroll
            for (int l = 0; l < BNODES; ++l) { segoff[l] = run; run += cnt64[l]; }
            segoff[BNODES] = run;
        }
        __syncthreads();
#pragma unroll
        for (int k = 0; k < CAP2 / 512; ++k)
            if (rnk[k] >= 0) recS[segoff[locl[k]] + rnk[k]] = rec[k];
        __syncthreads();

#pragma unroll
        for (int which = 0; which < 2; ++which) {
            int l = grp + which * 32;
            int s0 = segoff[l], s1 = segoff[l + 1];
            dcnt[which] += s1 - s0;
            int i = s0;
            for (; i + 4 <= s1; i += 4) {
                unsigned long long r0 = recS[i];
                unsigned long long r1 = recS[i + 1];
                unsigned long long r2 = recS[i + 2];
                unsigned long long r3 = recS[i + 3];
                float w0 = __uint_as_float((unsigned int)(r0 >> 32));
                float w1 = __uint_as_float((unsigned int)(r1 >> 32));
                float w2 = __uint_as_float((unsigned int)(r2 >> 32));
                float w3 = __uint_as_float((unsigned int)(r3 >> 32));
                int s0i = (unsigned int)r0 & 0xFFFF;
                int s1i = (unsigned int)r1 & 0xFFFF;
                int s2i = (unsigned int)r2 & 0xFFFF;
                int s3i = (unsigned int)r3 & 0xFFFF;
                uint4 u0 = xbf4[(size_t)s0i * 16 + lane];
                uint4 u1 = xbf4[(size_t)s1i * 16 + lane];
                uint4 u2 = xbf4[(size_t)s2i * 16 + lane];
                uint4 u3 = xbf4[(size_t)s3i * 16 + lane];
                accum8(acc[which], u0, w0);
                accum8(acc[which], u1, w1);
                accum8(acc[which], u2, w2);
                accum8(acc[which], u3, w3);
            }
            for (; i < s1; ++i) {
                unsigned long long ra = recS[i];
                float wa = __uint_as_float((unsigned int)(ra >> 32));
                int sa = (unsigned int)ra & 0xFFFF;
                uint4 ua = xbf4[(size_t)sa * 16 + lane];
                accum8(acc[which], ua, wa);
            }
        }
        __syncthreads();   // before next chunk overwrites recS
    }

    // writeout: bf16-pack; lane owns features lane*8..lane*8+7
#pragma unroll
    for (int which = 0; which < 2; ++which) {
        int n = n0 + grp + which * 32;
        if (n < N) {
            uint4 o;
            o.x = (bf16_rne(acc[which][1]) << 16) | bf16_rne(acc[which][0]);
            o.y = (bf16_rne(acc[which][3]) << 16) | bf16_rne(acc[which][2]);
            o.z = (bf16_rne(acc[which][5]) << 16) | bf16_rne(acc[which][4]);
            o.w = (bf16_rne(acc[which][7]) << 16) | bf16_rne(acc[which][6]);
            agg_bf4[(size_t)n * 16 + lane] = o;
            if (lane == 0) deg[n] = dcnt[which];
        }
    }
}

// ---------------- finalize: tiled GEMM, out = x + (agg/deg) @ W --------------
// W is staged through LDS (32 KB halves) -- NEVER stream W per-thread from L2
// (R6/R9 both lost >2x to exactly that).
__global__ __launch_bounds__(256) void finalize_kernel(
    const float* __restrict__ x, const uint4* __restrict__ agg_bf4,
    const int* __restrict__ deg, const float* __restrict__ Wm,
    float* __restrict__ out, int N) {
    __shared__ float aggS[64 * 128];  // 32 KB
    __shared__ float Ws[128 * 64];    // 32 KB
    const int n0 = blockIdx.x * 64;

    for (int i = threadIdx.x; i < 64 * 16; i += 256) {
        int r = i >> 4;
        int q = i & 15;
        int n = n0 + r;
        uint4 u = make_uint4(0u, 0u, 0u, 0u);
        if (n < N) u = agg_bf4[(size_t)n * 16 + q];
        float4 f0, f1;
        f0.x = __uint_as_float(u.x << 16);
        f0.y = __uint_as_float(u.x & 0xFFFF0000u);
        f0.z = __uint_as_float(u.y << 16);
        f0.w = __uint_as_float(u.y & 0xFFFF0000u);
        f1.x = __uint_as_float(u.z << 16);
        f1.y = __uint_as_float(u.z & 0xFFFF0000u);
        f1.z = __uint_as_float(u.w << 16);
        f1.w = __uint_as_float(u.w & 0xFFFF0000u);
        int m = (r >> 2) & 7;
        ((float4*)aggS)[r * 32 + ((2 * q) ^ m)] = f0;
        ((float4*)aggS)[r * 32 + ((2 * q + 1) ^ m)] = f1;
    }

    const int tc = threadIdx.x & 15;
    const int tr = threadIdx.x >> 4;

    float invd[4];
#pragma unroll
    for (int i = 0; i < 4; ++i) {
        int n = n0 + 4 * tr + i;
        float degf = 1.0f;
        if (n < N) degf = fmaxf((float)deg[n], 1.0f);
        invd[i] = 1.0f / degf;
    }

    for (int h = 0; h < 2; ++h) {
        for (int i = threadIdx.x; i < 128 * 16; i += 256) {
            int k = i >> 4;
            int j4 = i & 15;
            ((float4*)Ws)[k * 16 + j4] = ((const float4*)Wm)[k * 32 + h * 16 + j4];
        }
        __syncthreads();

        float acc[4][4];
#pragma unroll
        for (int i = 0; i < 4; ++i)
#pragma unroll
            for (int c = 0; c < 4; ++c) acc[i][c] = 0.f;

#pragma unroll 4
        for (int k0 = 0; k0 < 128; k0 += 4) {
            float4 ar4[4];
            const int chunk = (k0 >> 2) ^ (tr & 7);
#pragma unroll
            for (int i = 0; i < 4; ++i) {
                int r = 4 * tr + i;
                ar4[i] = ((const float4*)aggS)[r * 32 + chunk];
            }
            float4 wv4[4];
#pragma unroll
            for (int kk = 0; kk < 4; ++kk)
                wv4[kk] = *(const float4*)&Ws[(k0 + kk) * 64 + tc * 4];

            float wvv[4][4];
#pragma unroll
            for (int kk = 0; kk < 4; ++kk) {
                wvv[kk][0] = wv4[kk].x; wvv[kk][1] = wv4[kk].y;
                wvv[kk][2] = wv4[kk].z; wvv[kk][3] = wv4[kk].w;
            }
#pragma unroll
            for (int i = 0; i < 4; ++i) {
                float av[4] = {ar4[i].x, ar4[i].y, ar4[i].z, ar4[i].w};
#pragma unroll
                for (int kk = 0; kk < 4; ++kk)
#pragma unroll
                    for (int c = 0; c < 4; ++c)
                        acc[i][c] = fmaf(av[kk], wvv[kk][c], acc[i][c]);
            }
        }

#pragma unroll
        for (int i = 0; i < 4; ++i) {
            int n = n0 + 4 * tr + i;
            if (n < N) {
                size_t base = (size_t)n * FEAT + h * 64 + tc * 4;
                float4 xv = *(const float4*)&x[base];
                float4 o;
                o.x = xv.x + invd[i] * acc[i][0];
                o.y = xv.y + invd[i] * acc[i][1];
                o.z = xv.z + invd[i] * acc[i][2];
                o.w = xv.w + invd[i] * acc[i][3];
                *(float4*)&out[base] = o;
            }
        }
        __syncthreads();
    }
}

// ---------------- fallback (atomic path) ---------------
__global__ __launch_bounds__(256) void scatter_fallback(
    const float4* __restrict__ x4, const int* __restrict__ sender,
    const int* __restrict__ receiver, const float* __restrict__ edge_len,
    const float* __restrict__ log_scale, const float* __restrict__ filter_w,
    const float* __restrict__ filter_b, float* __restrict__ agg,
    float* __restrict__ deg, int E) {
    int gid = blockIdx.x * 256 + threadIdx.x;
    int e = gid >> 5;
    if (e >= E) return;
    int lane = gid & 31;
    int s = sender[e];
    int r = receiver[e];
    float scale = expf(log_scale[0]) + 1e-6f;
    float w = edge_weight(edge_len[e], scale, filter_w[0], filter_b[0]);
    float4 xv = x4[s * (FEAT / 4) + lane];
    float* dst = agg + (size_t)r * FEAT + lane * 4;
    unsafeAtomicAdd(dst + 0, w * xv.x);
    unsafeAtomicAdd(dst + 1, w * xv.y);
    unsafeAtomicAdd(dst + 2, w * xv.z);
    unsafeAtomicAdd(dst + 3, w * xv.w);
    if (lane == 0) unsafeAtomicAdd(&deg[r], 1.0f);
}

__global__ __launch_bounds__(256) void finalize_fallback(
    const float* __restrict__ x, const float* __restrict__ agg,
    const float* __restrict__ deg, const float* __restrict__ Wm,
    float* __restrict__ out, int N) {
    __shared__ float Wsf[FEAT * FEAT];
    for (int i = threadIdx.x * 4; i < FEAT * FEAT; i += 256 * 4)
        *(float4*)&Wsf[i] = *(const float4*)&Wm[i];
    __syncthreads();
    int half = threadIdx.x >> 7;
    int j = threadIdx.x & (FEAT - 1);
    for (int n0 = blockIdx.x * 2; n0 < N; n0 += gridDim.x * 2) {
        int n = n0 + half;
        if (n < N) {
            const float* arow = agg + (size_t)n * FEAT;
            float acc = 0.0f;
#pragma unroll 16
            for (int k = 0; k < FEAT; ++k) acc = fmaf(arow[k], Wsf[k * FEAT + j], acc);
            float invd = 1.0f / fmaxf(deg[n], 1.0f);
            size_t idx = (size_t)n * FEAT + j;
            out[idx] = x[idx] + invd * acc;
        }
    }
}

extern "C" void kernel_launch(void* const* d_in, const int* in_sizes, int n_in,
                              void* d_out, int out_size, void* d_ws, size_t ws_size,
                              hipStream_t stream) {
    const float* x         = (const float*)d_in[0];
    const int*   ei        = (const int*)d_in[1];
    const float* edge_len  = (const float*)d_in[2];
    const float* W_mix     = (const float*)d_in[3];
    const float* log_scale = (const float*)d_in[4];
    const float* filter_w  = (const float*)d_in[5];
    const float* filter_b  = (const float*)d_in[6];
    float* out = (float*)d_out;

    const int N = in_sizes[0] / FEAT;
    const int E = in_sizes[1] / 2;
    const int* sender   = ei;
    const int* receiver = ei + E;
    const int nbuck = (N + BNODES - 1) >> BSHIFT;
    const int nchunk = (E + EPB - 1) / EPB;

    size_t xbf_bytes  = (size_t)N * FEAT * 2;
    size_t aggb_bytes = (size_t)N * FEAT * 2;
    size_t gcnt_bytes = (((size_t)nbuck * 4) + 63) & ~(size_t)63;
    size_t deg_bytes  = (((size_t)N * 4) + 63) & ~(size_t)63;

    // bucket region capacity: want 2*mean+512; shrink to fit; floor mean+5sigma
    int mean = E / nbuck + 1;
    size_t head = xbf_bytes + aggb_bytes + gcnt_bytes + deg_bytes;
    size_t avail = (ws_size > head) ? ws_size - head : 0;
    int cap = (2 * mean + 512 + 63) & ~63;
    int capmax = (int)((avail / ((size_t)nbuck * 8)) & ~(size_t)63);
    if (cap > capmax) cap = capmax;
    int sigma5 = 5 * (int)sqrtf((float)mean) + 64;
    bool ok = (N <= 65536) && (nbuck <= NBUCK_MAX) && (cap >= mean + sigma5);

    if (ok) {
        char* p = (char*)d_ws;
        uint2* xbf    = (uint2*)p;                        p += xbf_bytes;
        uint4* agg_bf = (uint4*)p;                        p += aggb_bytes;
        int* gcnt     = (int*)p;                          p += gcnt_bytes;
        int* deg      = (int*)p;                          p += deg_bytes;
        unsigned long long* buf = (unsigned long long*)p;

        (void)hipMemsetAsync(gcnt, 0, (size_t)nbuck * sizeof(int), stream);

        int n4 = N * (FEAT / 4);
        int cblocks = (n4 + K1T - 1) / K1T;
        convert_scatter_kernel<<<nchunk + cblocks, K1T, 0, stream>>>(
            (const float4*)x, xbf, n4, sender, receiver, edge_len,
            log_scale, filter_w, filter_b, gcnt, buf, E, nbuck, cap, nchunk);
        bucket_sort_aggregate_kernel<<<nbuck, 512, 0, stream>>>(
            (const uint4*)xbf, buf, gcnt, agg_bf, deg, N, cap);
        int fblocks = (N + 63) / 64;
        finalize_kernel<<<fblocks, 256, 0, stream>>>(
            x, (const uint4*)agg_bf, deg, W_mix, out, N);
    } else {
        float* agg = (float*)d_ws;
        float* degf = agg + (size_t)N * FEAT;
        (void)hipMemsetAsync(agg, 0, ((size_t)N * FEAT + N) * sizeof(float), stream);
        int sblocks = (E * 32 + 255) / 256;
        scatter_fallback<<<sblocks, 256, 0, stream>>>(
            (const float4*)x, sender, receiver, edge_len,
            log_scale, filter_w, filter_b, agg, degf, E);
        finalize_fallback<<<512, 256, 0, stream>>>(x, agg, degf, W_mix, out, N);
    }
}

// Round 11
// 211.647 us; speedup vs baseline: 1.8556x; 1.0015x over previous
//
#include <hip/hip_runtime.h>
#include <math.h>

#define FEAT 128
#define BSHIFT 6            // 64 nodes per COARSE bucket
#define BNODES 64
#define CAP2 4096           // records per LDS sort chunk in K2 (32 KB):
                            // cap<=3584 -> every bucket is a SINGLE chunk
#define NBUCK_MAX 1024      // N <= 65536 -> nbuck <= 1024 (fits 10 bits)
#define EPB 4096            // edges per scatter chunk: 367 blocks at E=1.5M
#define K1T 512             // K1 threads: 8 waves/block -> 24 waves/CU at 3 blk

__device__ __forceinline__ float edge_weight(float d, float scale, float fw, float fb) {
    // scale already includes +1e-6
    float t = fmaxf(d / scale, 0.0f);
    float decay = expf(-t * t);
    float g = 1.0f / (1.0f + expf(-(d * fw + fb)));
    float w = decay * g;
    if (!isfinite(w)) w = 0.0f;
    return w;
}

__device__ __forceinline__ unsigned int bf16_rne(float f) {
    unsigned int b = __float_as_uint(f);
    return (b + 0x7FFFu + ((b >> 16) & 1u)) >> 16;
}

__device__ __forceinline__ void accum8(float acc[8], uint4 u, float w) {
    acc[0] = fmaf(w, __uint_as_float(u.x << 16), acc[0]);
    acc[1] = fmaf(w, __uint_as_float(u.x & 0xFFFF0000u), acc[1]);
    acc[2] = fmaf(w, __uint_as_float(u.y << 16), acc[2]);
    acc[3] = fmaf(w, __uint_as_float(u.y & 0xFFFF0000u), acc[3]);
    acc[4] = fmaf(w, __uint_as_float(u.z << 16), acc[4]);
    acc[5] = fmaf(w, __uint_as_float(u.z & 0xFFFF0000u), acc[5]);
    acc[6] = fmaf(w, __uint_as_float(u.w << 16), acc[6]);
    acc[7] = fmaf(w, __uint_as_float(u.w & 0xFFFF0000u), acc[7]);
}

// ==== K1: scatter chunks [0,nchunk) + convert blocks [nchunk,...). 512 thr.
// Scatter: LDS histogram -> LDS scan -> ONE global atomicAdd per bucket
// (reserve run) -> counting-sort records into LDS -> COALESCED writeout.
// Bucket id (10 bits) stashed in record bits 22..31 for the writeout.
__global__ __launch_bounds__(K1T) void convert_scatter_kernel(
    const float4* __restrict__ x4, uint2* __restrict__ xbf, int n4,
    const int* __restrict__ sender, const int* __restrict__ recv,
    const float* __restrict__ edge_len,
    const float* __restrict__ log_scale, const float* __restrict__ filter_w,
    const float* __restrict__ filter_b,
    int* __restrict__ gcnt, unsigned long long* __restrict__ buf,
    int E, int nbuck, int cap, int nchunk) {
    __shared__ unsigned long long recS[EPB];   // 32 KB
    __shared__ int cnt[NBUCK_MAX];             // histogram, then rank cursor
    __shared__ int segoff[NBUCK_MAX];          // local exclusive scan
    __shared__ int resbase[NBUCK_MAX];         // global run base (abs position)
    __shared__ int part[K1T];
    const int tid = threadIdx.x;

    if ((int)blockIdx.x >= nchunk) {            // ---- convert part ----
        int i = ((int)blockIdx.x - nchunk) * K1T + tid;
        if (i >= n4) return;
        float4 v = x4[i];
        uint2 o;
        o.x = (bf16_rne(v.y) << 16) | bf16_rne(v.x);
        o.y = (bf16_rne(v.w) << 16) | bf16_rne(v.z);
        xbf[i] = o;
        return;
    }

    // ---- scatter part ----
    const int c = blockIdx.x;
    for (int i = tid; i < nbuck; i += K1T) cnt[i] = 0;
    __syncthreads();
    const int base = c * EPB;
    const int end = min(base + EPB, E);
    const int cntE = end - base;
    for (int e = base + tid; e < end; e += K1T)
        atomicAdd(&cnt[recv[e] >> BSHIFT], 1);
    __syncthreads();

    // local exclusive scan over nbuck (<=1024) entries: 2 per thread
    {
        int i0 = tid * 2;
        int v0 = 0, v1 = 0;
        if (i0 < nbuck) {
            v0 = cnt[i0];
            v1 = (i0 + 1 < nbuck) ? cnt[i0 + 1] : 0;
        }
        int s = v0 + v1;
        part[tid] = s;
        __syncthreads();
        for (int d = 1; d < K1T; d <<= 1) {
            int t = (tid >= d) ? part[tid - d] : 0;
            __syncthreads();
            part[tid] += t;
            __syncthreads();
        }
        int run = part[tid] - s;
        if (i0 < nbuck) {
            segoff[i0] = run; run += v0;
            if (i0 + 1 < nbuck) segoff[i0 + 1] = run;
        }
    }
    __syncthreads();
    // reserve global runs + init rank cursors (cnt becomes the cursor)
    for (int i = tid; i < nbuck; i += K1T) {
        int cc = cnt[i];
        int b0 = cc ? atomicAdd(&gcnt[i], cc) : 0;
        resbase[i] = i * cap + b0;
        cnt[i] = segoff[i];
    }
    __syncthreads();

    // build records sorted-by-bucket in LDS
    float scale = expf(log_scale[0]) + 1e-6f;
    float fw = filter_w[0], fb = filter_b[0];
    for (int e = base + tid; e < end; e += K1T) {
        int r = recv[e];
        int s = sender[e];
        float w = edge_weight(edge_len[e], scale, fw, fb);
        int bk = r >> BSHIFT;
        int j = atomicAdd(&cnt[bk], 1);
        recS[j] = ((unsigned long long)__float_as_uint(w) << 32)
                | (unsigned int)(s & 0xFFFF)
                | ((unsigned int)(r & (BNODES - 1)) << 16)
                | ((unsigned int)(bk & 1023) << 22);
    }
    __syncthreads();

    // coalesced writeout: sorted slot j -> run position
    for (int j = tid; j < cntE; j += K1T) {
        unsigned long long rec = recS[j];
        int bk = ((unsigned int)rec >> 22) & 1023;
        int pos = resbase[bk] + (j - segoff[bk]);
        if (pos < (bk + 1) * cap)   // safety only; cap >= mean+5sigma
            buf[pos] = rec;
    }
}

// ==== K2: single-pass sort+aggregate. One 512-thread block per coarse
// bucket; 32 groups x 2 nodes. CAP2=4096 -> one sort chunk per bucket
// (half the barriers); gather is 8-deep for 8 outstanding loads/group.
__global__ __launch_bounds__(512) void bucket_sort_aggregate_kernel(
    const uint4* __restrict__ xbf4, const unsigned long long* __restrict__ buf,
    const int* __restrict__ gcnt, uint4* __restrict__ agg_bf4,
    int* __restrict__ deg, int N, int cap) {
    __shared__ unsigned long long recS[CAP2];   // 32 KB
    __shared__ int cnt64[BNODES];
    __shared__ int segoff[BNODES + 1];

    const int b = blockIdx.x;
    const int n0 = b << BSHIFT;
    const int tid = threadIdx.x;
    const int lane = tid & 15;
    const int grp = tid >> 4;   // 0..31
    const int lo = b * cap;
    const int hi = lo + min(gcnt[b], cap);

    float acc[2][8] = {{0.f,0.f,0.f,0.f,0.f,0.f,0.f,0.f},
                       {0.f,0.f,0.f,0.f,0.f,0.f,0.f,0.f}};
    int dcnt[2] = {0, 0};

    for (int pos = lo; pos < hi; pos += CAP2) {
        int cnt = min(CAP2, hi - pos);
        if (tid < BNODES) cnt64[tid] = 0;
        __syncthreads();

        unsigned long long rec[CAP2 / 512];
        int rnk[CAP2 / 512];
        int locl[CAP2 / 512];
#pragma unroll
        for (int k = 0; k < CAP2 / 512; ++k) {
            int i = k * 512 + tid;
            rnk[k] = -1;
            if (i < cnt) {
                unsigned long long r = buf[pos + i];
                int l = ((unsigned int)r >> 16) & (BNODES - 1);
                rec[k] = r;
                locl[k] = l;
                rnk[k] = atomicAdd(&cnt64[l], 1);
            }
        }
        __syncthreads();
        if (tid == 0) {
            int run = 0;
#pragma unroll
            for (int l = 0; l < BNODES; ++l) { segoff[l] = run; run += cnt64[l]; }
            segoff[BNODES] = run;
        }
        __syncthreads();
#pragma unroll
        for (int k = 0; k < CAP2 / 512; ++k)
            if (rnk[k] >= 0) recS[segoff[locl[k]] + rnk[k]] = rec[k];
        __syncthreads();

#pragma unroll
        for (int which = 0; which < 2; ++which) {
            int l = grp + which * 32;
            int s0 = segoff[l], s1 = segoff[l + 1];
            dcnt[which] += s1 - s0;
            int i = s0;
            // 8-deep: 8 gathers in flight per 16-lane group
            for (; i + 8 <= s1; i += 8) {
                unsigned long long r8[8];
#pragma unroll
                for (int k = 0; k < 8; ++k) r8[k] = recS[i + k];
                float w8[8];
                int s8[8];
#pragma unroll
                for (int k = 0; k < 8; ++k) {
                    w8[k] = __uint_as_float((unsigned int)(r8[k] >> 32));
                    s8[k] = (int)((unsigned int)r8[k] & 0xFFFFu);
                }
                uint4 u8[8];
#pragma unroll
                for (int k = 0; k < 8; ++k)
                    u8[k] = xbf4[(size_t)s8[k] * 16 + lane];
#pragma unroll
                for (int k = 0; k < 8; ++k) accum8(acc[which], u8[k], w8[k]);
            }
            for (; i < s1; ++i) {
                unsigned long long ra = recS[i];
                float wa = __uint_as_float((unsigned int)(ra >> 32));
                int sa = (unsigned int)ra & 0xFFFF;
                uint4 ua = xbf4[(size_t)sa * 16 + lane];
                accum8(acc[which], ua, wa);
            }
        }
        __syncthreads();   // before next chunk overwrites recS
    }

    // writeout: bf16-pack; lane owns features lane*8..lane*8+7
#pragma unroll
    for (int which = 0; which < 2; ++which) {
        int n = n0 + grp + which * 32;
        if (n < N) {
            uint4 o;
            o.x = (bf16_rne(acc[which][1]) << 16) | bf16_rne(acc[which][0]);
            o.y = (bf16_rne(acc[which][3]) << 16) | bf16_rne(acc[which][2]);
            o.z = (bf16_rne(acc[which][5]) << 16) | bf16_rne(acc[which][4]);
            o.w = (bf16_rne(acc[which][7]) << 16) | bf16_rne(acc[which][6]);
            agg_bf4[(size_t)n * 16 + lane] = o;
            if (lane == 0) deg[n] = dcnt[which];
        }
    }
}

// ---------------- finalize: tiled GEMM, out = x + (agg/deg) @ W --------------
// W is staged through LDS (32 KB halves) -- NEVER stream W per-thread from L2
// (R6/R9 both lost >2x to exactly that).
__global__ __launch_bounds__(256) void finalize_kernel(
    const float* __restrict__ x, const uint4* __restrict__ agg_bf4,
    const int* __restrict__ deg, const float* __restrict__ Wm,
    float* __restrict__ out, int N) {
    __shared__ float aggS[64 * 128];  // 32 KB
    __shared__ float Ws[128 * 64];    // 32 KB
    const int n0 = blockIdx.x * 64;

    for (int i = threadIdx.x; i < 64 * 16; i += 256) {
        int r = i >> 4;
        int q = i & 15;
        int n = n0 + r;
        uint4 u = make_uint4(0u, 0u, 0u, 0u);
        if (n < N) u = agg_bf4[(size_t)n * 16 + q];
        float4 f0, f1;
        f0.x = __uint_as_float(u.x << 16);
        f0.y = __uint_as_float(u.x & 0xFFFF0000u);
        f0.z = __uint_as_float(u.y << 16);
        f0.w = __uint_as_float(u.y & 0xFFFF0000u);
        f1.x = __uint_as_float(u.z << 16);
        f1.y = __uint_as_float(u.z & 0xFFFF0000u);
        f1.z = __uint_as_float(u.w << 16);
        f1.w = __uint_as_float(u.w & 0xFFFF0000u);
        int m = (r >> 2) & 7;
        ((float4*)aggS)[r * 32 + ((2 * q) ^ m)] = f0;
        ((float4*)aggS)[r * 32 + ((2 * q + 1) ^ m)] = f1;
    }

    const int tc = threadIdx.x & 15;
    const int tr = threadIdx.x >> 4;

    float invd[4];
#pragma unroll
    for (int i = 0; i < 4; ++i) {
        int n = n0 + 4 * tr + i;
        float degf = 1.0f;
        if (n < N) degf = fmaxf((float)deg[n], 1.0f);
        invd[i] = 1.0f / degf;
    }

    for (int h = 0; h < 2; ++h) {
        for (int i = threadIdx.x; i < 128 * 16; i += 256) {
            int k = i >> 4;
            int j4 = i & 15;
            ((float4*)Ws)[k * 16 + j4] = ((const float4*)Wm)[k * 32 + h * 16 + j4];
        }
        __syncthreads();

        float acc[4][4];
#pragma unroll
        for (int i = 0; i < 4; ++i)
#pragma unroll
            for (int c = 0; c < 4; ++c) acc[i][c] = 0.f;

#pragma unroll 4
        for (int k0 = 0; k0 < 128; k0 += 4) {
            float4 ar4[4];
            const int chunk = (k0 >> 2) ^ (tr & 7);
#pragma unroll
            for (int i = 0; i < 4; ++i) {
                int r = 4 * tr + i;
                ar4[i] = ((const float4*)aggS)[r * 32 + chunk];
            }
            float4 wv4[4];
#pragma unroll
            for (int kk = 0; kk < 4; ++kk)
                wv4[kk] = *(const float4*)&Ws[(k0 + kk) * 64 + tc * 4];

            float wvv[4][4];
#pragma unroll
            for (int kk = 0; kk < 4; ++kk) {
                wvv[kk][0] = wv4[kk].x; wvv[kk][1] = wv4[kk].y;
                wvv[kk][2] = wv4[kk].z; wvv[kk][3] = wv4[kk].w;
            }
#pragma unroll
            for (int i = 0; i < 4; ++i) {
                float av[4] = {ar4[i].x, ar4[i].y, ar4[i].z, ar4[i].w};
#pragma unroll
                for (int kk = 0; kk < 4; ++kk)
#pragma unroll
                    for (int c = 0; c < 4; ++c)
                        acc[i][c] = fmaf(av[kk], wvv[kk][c], acc[i][c]);
            }
        }

#pragma unroll
        for (int i = 0; i < 4; ++i) {
            int n = n0 + 4 * tr + i;
            if (n < N) {
                size_t base = (size_t)n * FEAT + h * 64 + tc * 4;
                float4 xv = *(const float4*)&x[base];
                float4 o;
                o.x = xv.x + invd[i] * acc[i][0];
                o.y = xv.y + invd[i] * acc[i][1];
                o.z = xv.z + invd[i] * acc[i][2];
                o.w = xv.w + invd[i] * acc[i][3];
                *(float4*)&out[base] = o;
            }
        }
        __syncthreads();
    }
}

// ---------------- fallback (atomic path) ---------------
__global__ __launch_bounds__(256) void scatter_fallback(
    const float4* __restrict__ x4, const int* __restrict__ sender,
    const int* __restrict__ receiver, const float* __restrict__ edge_len,
    const float* __restrict__ log_scale, const float* __restrict__ filter_w,
    const float* __restrict__ filter_b, float* __restrict__ agg,
    float* __restrict__ deg, int E) {
    int gid = blockIdx.x * 256 + threadIdx.x;
    int e = gid >> 5;
    if (e >= E) return;
    int lane = gid & 31;
    int s = sender[e];
    int r = receiver[e];
    float scale = expf(log_scale[0]) + 1e-6f;
    float w = edge_weight(edge_len[e], scale, filter_w[0], filter_b[0]);
    float4 xv = x4[s * (FEAT / 4) + lane];
    float* dst = agg + (size_t)r * FEAT + lane * 4;
    unsafeAtomicAdd(dst + 0, w * xv.x);
    unsafeAtomicAdd(dst + 1, w * xv.y);
    unsafeAtomicAdd(dst + 2, w * xv.z);
    unsafeAtomicAdd(dst + 3, w * xv.w);
    if (lane == 0) unsafeAtomicAdd(&deg[r], 1.0f);
}

__global__ __launch_bounds__(256) void finalize_fallback(
    const float* __restrict__ x, const float* __restrict__ agg,
    const float* __restrict__ deg, const float* __restrict__ Wm,
    float* __restrict__ out, int N) {
    __shared__ float Wsf[FEAT * FEAT];
    for (int i = threadIdx.x * 4; i < FEAT * FEAT; i += 256 * 4)
        *(float4*)&Wsf[i] = *(const float4*)&Wm[i];
    __syncthreads();
    int half = threadIdx.x >> 7;
    int j = threadIdx.x & (FEAT - 1);
    for (int n0 = blockIdx.x * 2; n0 < N; n0 += gridDim.x * 2) {
        int n = n0 + half;
        if (n < N) {
            const float* arow = agg + (size_t)n * FEAT;
            float acc = 0.0f;
#pragma unroll 16
            for (int k = 0; k < FEAT; ++k) acc = fmaf(arow[k], Wsf[k * FEAT + j], acc);
            float invd = 1.0f / fmaxf(deg[n], 1.0f);
            size_t idx = (size_t)n * FEAT + j;
            out[idx] = x[idx] + invd * acc;
        }
    }
}

extern "C" void kernel_launch(void* const* d_in, const int* in_sizes, int n_in,
                              void* d_out, int out_size, void* d_ws, size_t ws_size,
                              hipStream_t stream) {
    const float* x         = (const float*)d_in[0];
    const int*   ei        = (const int*)d_in[1];
    const float* edge_len  = (const float*)d_in[2];
    const float* W_mix     = (const float*)d_in[3];
    const float* log_scale = (const float*)d_in[4];
    const float* filter_w  = (const float*)d_in[5];
    const float* filter_b  = (const float*)d_in[6];
    float* out = (float*)d_out;

    const int N = in_sizes[0] / FEAT;
    const int E = in_sizes[1] / 2;
    const int* sender   = ei;
    const int* receiver = ei + E;
    const int nbuck = (N + BNODES - 1) >> BSHIFT;
    const int nchunk = (E + EPB - 1) / EPB;

    size_t xbf_bytes  = (size_t)N * FEAT * 2;
    size_t aggb_bytes = (size_t)N * FEAT * 2;
    size_t gcnt_bytes = (((size_t)nbuck * 4) + 63) & ~(size_t)63;
    size_t deg_bytes  = (((size_t)N * 4) + 63) & ~(size_t)63;

    // bucket region capacity: want 2*mean+512; shrink to fit; floor mean+5sigma
    int mean = E / nbuck + 1;
    size_t head = xbf_bytes + aggb_bytes + gcnt_bytes + deg_bytes;
    size_t avail = (ws_size > head) ? ws_size - head : 0;
    int cap = (2 * mean + 512 + 63) & ~63;
    int capmax = (int)((avail / ((size_t)nbuck * 8)) & ~(size_t)63);
    if (cap > capmax) cap = capmax;
    int sigma5 = 5 * (int)sqrtf((float)mean) + 64;
    bool ok = (N <= 65536) && (nbuck <= NBUCK_MAX) && (cap >= mean + sigma5);

    if (ok) {
        char* p = (char*)d_ws;
        uint2* xbf    = (uint2*)p;                        p += xbf_bytes;
        uint4* agg_bf = (uint4*)p;                        p += aggb_bytes;
        int* gcnt     = (int*)p;                          p += gcnt_bytes;
        int* deg      = (int*)p;                          p += deg_bytes;
        unsigned long long* buf = (unsigned long long*)p;

        (void)hipMemsetAsync(gcnt, 0, (size_t)nbuck * sizeof(int), stream);

        int n4 = N * (FEAT / 4);
        int cblocks = (n4 + K1T - 1) / K1T;
        convert_scatter_kernel<<<nchunk + cblocks, K1T, 0, stream>>>(
            (const float4*)x, xbf, n4, sender, receiver, edge_len,
            log_scale, filter_w, filter_b, gcnt, buf, E, nbuck, cap, nchunk);
        bucket_sort_aggregate_kernel<<<nbuck, 512, 0, stream>>>(
            (const uint4*)xbf, buf, gcnt, agg_bf, deg, N, cap);
        int fblocks = (N + 63) / 64;
        finalize_kernel<<<fblocks, 256, 0, stream>>>(
            x, (const uint4*)agg_bf, deg, W_mix, out, N);
    } else {
        float* agg = (float*)d_ws;
        float* degf = agg + (size_t)N * FEAT;
        (void)hipMemsetAsync(agg, 0, ((size_t)N * FEAT + N) * sizeof(float), stream);
        int sblocks = (E * 32 + 255) / 256;
        scatter_fallback<<<sblocks, 256, 0, stream>>>(
            (const float4*)x, sender, receiver, edge_len,
            log_scale, filter_w, filter_b, agg, degf, E);
        finalize_fallback<<<512, 256, 0, stream>>>(x, agg, degf, W_mix, out, N);
    }
}

// Round 12
// 209.719 us; speedup vs baseline: 1.8727x; 1.0092x over previous
//
#include <hip/hip_runtime.h>
#include <math.h>

#define FEAT 128
#define BSHIFT 6            // 64 nodes per COARSE bucket
#define BNODES 64
#define CAP2 4096           // records per LDS sort chunk in K2 (32 KB):
                            // cap<=3584 -> every bucket is a SINGLE chunk
#define NBUCK_MAX 1024      // N <= 65536 -> nbuck <= 1024 (fits 10 bits)
#define EPB 4096            // edges per scatter chunk: 367 blocks at E=1.5M
#define K1T 512             // K1 threads: 8 waves/block -> 24 waves/CU at 3 blk

__device__ __forceinline__ float edge_weight(float d, float scale, float fw, float fb) {
    // scale already includes +1e-6
    float t = fmaxf(d / scale, 0.0f);
    float decay = expf(-t * t);
    float g = 1.0f / (1.0f + expf(-(d * fw + fb)));
    float w = decay * g;
    if (!isfinite(w)) w = 0.0f;
    return w;
}

__device__ __forceinline__ unsigned int bf16_rne(float f) {
    unsigned int b = __float_as_uint(f);
    return (b + 0x7FFFu + ((b >> 16) & 1u)) >> 16;
}

__device__ __forceinline__ void accum8(float acc[8], uint4 u, float w) {
    acc[0] = fmaf(w, __uint_as_float(u.x << 16), acc[0]);
    acc[1] = fmaf(w, __uint_as_float(u.x & 0xFFFF0000u), acc[1]);
    acc[2] = fmaf(w, __uint_as_float(u.y << 16), acc[2]);
    acc[3] = fmaf(w, __uint_as_float(u.y & 0xFFFF0000u), acc[3]);
    acc[4] = fmaf(w, __uint_as_float(u.z << 16), acc[4]);
    acc[5] = fmaf(w, __uint_as_float(u.z & 0xFFFF0000u), acc[5]);
    acc[6] = fmaf(w, __uint_as_float(u.w << 16), acc[6]);
    acc[7] = fmaf(w, __uint_as_float(u.w & 0xFFFF0000u), acc[7]);
}

// ==== K1: scatter chunks [0,nchunk) + convert blocks [nchunk,...). 512 thr.
// Scatter: LDS histogram -> LDS scan -> ONE global atomicAdd per bucket
// (reserve run) -> counting-sort records into LDS -> COALESCED writeout.
// Bucket id (10 bits) stashed in record bits 22..31 for the writeout.
__global__ __launch_bounds__(K1T) void convert_scatter_kernel(
    const float4* __restrict__ x4, uint2* __restrict__ xbf, int n4,
    const int* __restrict__ sender, const int* __restrict__ recv,
    const float* __restrict__ edge_len,
    const float* __restrict__ log_scale, const float* __restrict__ filter_w,
    const float* __restrict__ filter_b,
    int* __restrict__ gcnt, unsigned long long* __restrict__ buf,
    int E, int nbuck, int cap, int nchunk) {
    __shared__ unsigned long long recS[EPB];   // 32 KB
    __shared__ int cnt[NBUCK_MAX];             // histogram, then rank cursor
    __shared__ int segoff[NBUCK_MAX];          // local exclusive scan
    __shared__ int resbase[NBUCK_MAX];         // global run base (abs position)
    __shared__ int part[K1T];
    const int tid = threadIdx.x;

    if ((int)blockIdx.x >= nchunk) {            // ---- convert part ----
        int i = ((int)blockIdx.x - nchunk) * K1T + tid;
        if (i >= n4) return;
        float4 v = x4[i];
        uint2 o;
        o.x = (bf16_rne(v.y) << 16) | bf16_rne(v.x);
        o.y = (bf16_rne(v.w) << 16) | bf16_rne(v.z);
        xbf[i] = o;
        return;
    }

    // ---- scatter part ----
    const int c = blockIdx.x;
    for (int i = tid; i < nbuck; i += K1T) cnt[i] = 0;
    __syncthreads();
    const int base = c * EPB;
    const int end = min(base + EPB, E);
    const int cntE = end - base;
    for (int e = base + tid; e < end; e += K1T)
        atomicAdd(&cnt[recv[e] >> BSHIFT], 1);
    __syncthreads();

    // local exclusive scan over nbuck (<=1024) entries: 2 per thread
    {
        int i0 = tid * 2;
        int v0 = 0, v1 = 0;
        if (i0 < nbuck) {
            v0 = cnt[i0];
            v1 = (i0 + 1 < nbuck) ? cnt[i0 + 1] : 0;
        }
        int s = v0 + v1;
        part[tid] = s;
        __syncthreads();
        for (int d = 1; d < K1T; d <<= 1) {
            int t = (tid >= d) ? part[tid - d] : 0;
            __syncthreads();
            part[tid] += t;
            __syncthreads();
        }
        int run = part[tid] - s;
        if (i0 < nbuck) {
            segoff[i0] = run; run += v0;
            if (i0 + 1 < nbuck) segoff[i0 + 1] = run;
        }
    }
    __syncthreads();
    // reserve global runs + init rank cursors (cnt becomes the cursor)
    for (int i = tid; i < nbuck; i += K1T) {
        int cc = cnt[i];
        int b0 = cc ? atomicAdd(&gcnt[i], cc) : 0;
        resbase[i] = i * cap + b0;
        cnt[i] = segoff[i];
    }
    __syncthreads();

    // build records sorted-by-bucket in LDS
    float scale = expf(log_scale[0]) + 1e-6f;
    float fw = filter_w[0], fb = filter_b[0];
    for (int e = base + tid; e < end; e += K1T) {
        int r = recv[e];
        int s = sender[e];
        float w = edge_weight(edge_len[e], scale, fw, fb);
        int bk = r >> BSHIFT;
        int j = atomicAdd(&cnt[bk], 1);
        recS[j] = ((unsigned long long)__float_as_uint(w) << 32)
                | (unsigned int)(s & 0xFFFF)
                | ((unsigned int)(r & (BNODES - 1)) << 16)
                | ((unsigned int)(bk & 1023) << 22);
    }
    __syncthreads();

    // coalesced writeout: sorted slot j -> run position
    for (int j = tid; j < cntE; j += K1T) {
        unsigned long long rec = recS[j];
        int bk = ((unsigned int)rec >> 22) & 1023;
        int pos = resbase[bk] + (j - segoff[bk]);
        if (pos < (bk + 1) * cap)   // safety only; cap >= mean+5sigma
            buf[pos] = rec;
    }
}

// ==== K2: single-pass sort+aggregate. One 512-thread block per coarse
// bucket; 32 groups x 2 nodes. CAP2=4096 -> one sort chunk per bucket
// (half the barriers, R11 win); gather kept 4-deep: VGPR ~40 so 4 blocks
// x 8 waves = full 32 waves/CU (R11's 8-deep cost 64 VGPR -> occ 30%).
__global__ __launch_bounds__(512) void bucket_sort_aggregate_kernel(
    const uint4* __restrict__ xbf4, const unsigned long long* __restrict__ buf,
    const int* __restrict__ gcnt, uint4* __restrict__ agg_bf4,
    int* __restrict__ deg, int N, int cap) {
    __shared__ unsigned long long recS[CAP2];   // 32 KB
    __shared__ int cnt64[BNODES];
    __shared__ int segoff[BNODES + 1];

    const int b = blockIdx.x;
    const int n0 = b << BSHIFT;
    const int tid = threadIdx.x;
    const int lane = tid & 15;
    const int grp = tid >> 4;   // 0..31
    const int lo = b * cap;
    const int hi = lo + min(gcnt[b], cap);

    float acc[2][8] = {{0.f,0.f,0.f,0.f,0.f,0.f,0.f,0.f},
                       {0.f,0.f,0.f,0.f,0.f,0.f,0.f,0.f}};
    int dcnt[2] = {0, 0};

    for (int pos = lo; pos < hi; pos += CAP2) {
        int cnt = min(CAP2, hi - pos);
        if (tid < BNODES) cnt64[tid] = 0;
        __syncthreads();

        unsigned long long rec[CAP2 / 512];
        int rnk[CAP2 / 512];
        int locl[CAP2 / 512];
#pragma unroll
        for (int k = 0; k < CAP2 / 512; ++k) {
            int i = k * 512 + tid;
            rnk[k] = -1;
            if (i < cnt) {
                unsigned long long r = buf[pos + i];
                int l = ((unsigned int)r >> 16) & (BNODES - 1);
                rec[k] = r;
                locl[k] = l;
                rnk[k] = atomicAdd(&cnt64[l], 1);
            }
        }
        __syncthreads();
        if (tid == 0) {
            int run = 0;
#pragma unroll
            for (int l = 0; l < BNODES; ++l) { segoff[l] = run; run += cnt64[l]; }
            segoff[BNODES] = run;
        }
        __syncthreads();
#pragma unroll
        for (int k = 0; k < CAP2 / 512; ++k)
            if (rnk[k] >= 0) recS[segoff[locl[k]] + rnk[k]] = rec[k];
        __syncthreads();

#pragma unroll
        for (int which = 0; which < 2; ++which) {
            int l = grp + which * 32;
            int s0 = segoff[l], s1 = segoff[l + 1];
            dcnt[which] += s1 - s0;
            int i = s0;
            for (; i + 4 <= s1; i += 4) {
                unsigned long long r0 = recS[i];
                unsigned long long r1 = recS[i + 1];
                unsigned long long r2 = recS[i + 2];
                unsigned long long r3 = recS[i + 3];
                float w0 = __uint_as_float((unsigned int)(r0 >> 32));
                float w1 = __uint_as_float((unsigned int)(r1 >> 32));
                float w2 = __uint_as_float((unsigned int)(r2 >> 32));
                float w3 = __uint_as_float((unsigned int)(r3 >> 32));
                int s0i = (unsigned int)r0 & 0xFFFF;
                int s1i = (unsigned int)r1 & 0xFFFF;
                int s2i = (unsigned int)r2 & 0xFFFF;
                int s3i = (unsigned int)r3 & 0xFFFF;
                uint4 u0 = xbf4[(size_t)s0i * 16 + lane];
                uint4 u1 = xbf4[(size_t)s1i * 16 + lane];
                uint4 u2 = xbf4[(size_t)s2i * 16 + lane];
                uint4 u3 = xbf4[(size_t)s3i * 16 + lane];
                accum8(acc[which], u0, w0);
                accum8(acc[which], u1, w1);
                accum8(acc[which], u2, w2);
                accum8(acc[which], u3, w3);
            }
            for (; i < s1; ++i) {
                unsigned long long ra = recS[i];
                float wa = __uint_as_float((unsigned int)(ra >> 32));
                int sa = (unsigned int)ra & 0xFFFF;
                uint4 ua = xbf4[(size_t)sa * 16 + lane];
                accum8(acc[which], ua, wa);
            }
        }
        __syncthreads();   // before next chunk overwrites recS
    }

    // writeout: bf16-pack; lane owns features lane*8..lane*8+7
#pragma unroll
    for (int which = 0; which < 2; ++which) {
        int n = n0 + grp + which * 32;
        if (n < N) {
            uint4 o;
            o.x = (bf16_rne(acc[which][1]) << 16) | bf16_rne(acc[which][0]);
            o.y = (bf16_rne(acc[which][3]) << 16) | bf16_rne(acc[which][2]);
            o.z = (bf16_rne(acc[which][5]) << 16) | bf16_rne(acc[which][4]);
            o.w = (bf16_rne(acc[which][7]) << 16) | bf16_rne(acc[which][6]);
            agg_bf4[(size_t)n * 16 + lane] = o;
            if (lane == 0) deg[n] = dcnt[which];
        }
    }
}

// ---------------- finalize: tiled GEMM, out = x + (agg/deg) @ W --------------
// W is staged through LDS (32 KB halves) -- NEVER stream W per-thread from L2
// (R6/R9 both lost >2x to exactly that).
__global__ __launch_bounds__(256) void finalize_kernel(
    const float* __restrict__ x, const uint4* __restrict__ agg_bf4,
    const int* __restrict__ deg, const float* __restrict__ Wm,
    float* __restrict__ out, int N) {
    __shared__ float aggS[64 * 128];  // 32 KB
    __shared__ float Ws[128 * 64];    // 32 KB
    const int n0 = blockIdx.x * 64;

    for (int i = threadIdx.x; i < 64 * 16; i += 256) {
        int r = i >> 4;
        int q = i & 15;
        int n = n0 + r;
        uint4 u = make_uint4(0u, 0u, 0u, 0u);
        if (n < N) u = agg_bf4[(size_t)n * 16 + q];
        float4 f0, f1;
        f0.x = __uint_as_float(u.x << 16);
        f0.y = __uint_as_float(u.x & 0xFFFF0000u);
        f0.z = __uint_as_float(u.y << 16);
        f0.w = __uint_as_float(u.y & 0xFFFF0000u);
        f1.x = __uint_as_float(u.z << 16);
        f1.y = __uint_as_float(u.z & 0xFFFF0000u);
        f1.z = __uint_as_float(u.w << 16);
        f1.w = __uint_as_float(u.w & 0xFFFF0000u);
        int m = (r >> 2) & 7;
        ((float4*)aggS)[r * 32 + ((2 * q) ^ m)] = f0;
        ((float4*)aggS)[r * 32 + ((2 * q + 1) ^ m)] = f1;
    }

    const int tc = threadIdx.x & 15;
    const int tr = threadIdx.x >> 4;

    float invd[4];
#pragma unroll
    for (int i = 0; i < 4; ++i) {
        int n = n0 + 4 * tr + i;
        float degf = 1.0f;
        if (n < N) degf = fmaxf((float)deg[n], 1.0f);
        invd[i] = 1.0f / degf;
    }

    for (int h = 0; h < 2; ++h) {
        for (int i = threadIdx.x; i < 128 * 16; i += 256) {
            int k = i >> 4;
            int j4 = i & 15;
            ((float4*)Ws)[k * 16 + j4] = ((const float4*)Wm)[k * 32 + h * 16 + j4];
        }
        __syncthreads();

        float acc[4][4];
#pragma unroll
        for (int i = 0; i < 4; ++i)
#pragma unroll
            for (int c = 0; c < 4; ++c) acc[i][c] = 0.f;

#pragma unroll 4
        for (int k0 = 0; k0 < 128; k0 += 4) {
            float4 ar4[4];
            const int chunk = (k0 >> 2) ^ (tr & 7);
#pragma unroll
            for (int i = 0; i < 4; ++i) {
                int r = 4 * tr + i;
                ar4[i] = ((const float4*)aggS)[r * 32 + chunk];
            }
            float4 wv4[4];
#pragma unroll
            for (int kk = 0; kk < 4; ++kk)
                wv4[kk] = *(const float4*)&Ws[(k0 + kk) * 64 + tc * 4];

            float wvv[4][4];
#pragma unroll
            for (int kk = 0; kk < 4; ++kk) {
                wvv[kk][0] = wv4[kk].x; wvv[kk][1] = wv4[kk].y;
                wvv[kk][2] = wv4[kk].z; wvv[kk][3] = wv4[kk].w;
            }
#pragma unroll
            for (int i = 0; i < 4; ++i) {
                float av[4] = {ar4[i].x, ar4[i].y, ar4[i].z, ar4[i].w};
#pragma unroll
                for (int kk = 0; kk < 4; ++kk)
#pragma unroll
                    for (int c = 0; c < 4; ++c)
                        acc[i][c] = fmaf(av[kk], wvv[kk][c], acc[i][c]);
            }
        }

#pragma unroll
        for (int i = 0; i < 4; ++i) {
            int n = n0 + 4 * tr + i;
            if (n < N) {
                size_t base = (size_t)n * FEAT + h * 64 + tc * 4;
                float4 xv = *(const float4*)&x[base];
                float4 o;
                o.x = xv.x + invd[i] * acc[i][0];
                o.y = xv.y + invd[i] * acc[i][1];
                o.z = xv.z + invd[i] * acc[i][2];
                o.w = xv.w + invd[i] * acc[i][3];
                *(float4*)&out[base] = o;
            }
        }
        __syncthreads();
    }
}

// ---------------- fallback (atomic path) ---------------
__global__ __launch_bounds__(256) void scatter_fallback(
    const float4* __restrict__ x4, const int* __restrict__ sender,
    const int* __restrict__ receiver, const float* __restrict__ edge_len,
    const float* __restrict__ log_scale, const float* __restrict__ filter_w,
    const float* __restrict__ filter_b, float* __restrict__ agg,
    float* __restrict__ deg, int E) {
    int gid = blockIdx.x * 256 + threadIdx.x;
    int e = gid >> 5;
    if (e >= E) return;
    int lane = gid & 31;
    int s = sender[e];
    int r = receiver[e];
    float scale = expf(log_scale[0]) + 1e-6f;
    float w = edge_weight(edge_len[e], scale, filter_w[0], filter_b[0]);
    float4 xv = x4[s * (FEAT / 4) + lane];
    float* dst = agg + (size_t)r * FEAT + lane * 4;
    unsafeAtomicAdd(dst + 0, w * xv.x);
    unsafeAtomicAdd(dst + 1, w * xv.y);
    unsafeAtomicAdd(dst + 2, w * xv.z);
    unsafeAtomicAdd(dst + 3, w * xv.w);
    if (lane == 0) unsafeAtomicAdd(&deg[r], 1.0f);
}

__global__ __launch_bounds__(256) void finalize_fallback(
    const float* __restrict__ x, const float* __restrict__ agg,
    const float* __restrict__ deg, const float* __restrict__ Wm,
    float* __restrict__ out, int N) {
    __shared__ float Wsf[FEAT * FEAT];
    for (int i = threadIdx.x * 4; i < FEAT * FEAT; i += 256 * 4)
        *(float4*)&Wsf[i] = *(const float4*)&Wm[i];
    __syncthreads();
    int half = threadIdx.x >> 7;
    int j = threadIdx.x & (FEAT - 1);
    for (int n0 = blockIdx.x * 2; n0 < N; n0 += gridDim.x * 2) {
        int n = n0 + half;
        if (n < N) {
            const float* arow = agg + (size_t)n * FEAT;
            float acc = 0.0f;
#pragma unroll 16
            for (int k = 0; k < FEAT; ++k) acc = fmaf(arow[k], Wsf[k * FEAT + j], acc);
            float invd = 1.0f / fmaxf(deg[n], 1.0f);
            size_t idx = (size_t)n * FEAT + j;
            out[idx] = x[idx] + invd * acc;
        }
    }
}

extern "C" void kernel_launch(void* const* d_in, const int* in_sizes, int n_in,
                              void* d_out, int out_size, void* d_ws, size_t ws_size,
                              hipStream_t stream) {
    const float* x         = (const float*)d_in[0];
    const int*   ei        = (const int*)d_in[1];
    const float* edge_len  = (const float*)d_in[2];
    const float* W_mix     = (const float*)d_in[3];
    const float* log_scale = (const float*)d_in[4];
    const float* filter_w  = (const float*)d_in[5];
    const float* filter_b  = (const float*)d_in[6];
    float* out = (float*)d_out;

    const int N = in_sizes[0] / FEAT;
    const int E = in_sizes[1] / 2;
    const int* sender   = ei;
    const int* receiver = ei + E;
    const int nbuck = (N + BNODES - 1) >> BSHIFT;
    const int nchunk = (E + EPB - 1) / EPB;

    size_t xbf_bytes  = (size_t)N * FEAT * 2;
    size_t aggb_bytes = (size_t)N * FEAT * 2;
    size_t gcnt_bytes = (((size_t)nbuck * 4) + 63) & ~(size_t)63;
    size_t deg_bytes  = (((size_t)N * 4) + 63) & ~(size_t)63;

    // bucket region capacity: want 2*mean+512; shrink to fit; floor mean+5sigma
    int mean = E / nbuck + 1;
    size_t head = xbf_bytes + aggb_bytes + gcnt_bytes + deg_bytes;
    size_t avail = (ws_size > head) ? ws_size - head : 0;
    int cap = (2 * mean + 512 + 63) & ~63;
    int capmax = (int)((avail / ((size_t)nbuck * 8)) & ~(size_t)63);
    if (cap > capmax) cap = capmax;
    int sigma5 = 5 * (int)sqrtf((float)mean) + 64;
    bool ok = (N <= 65536) && (nbuck <= NBUCK_MAX) && (cap >= mean + sigma5);

    if (ok) {
        char* p = (char*)d_ws;
        uint2* xbf    = (uint2*)p;                        p += xbf_bytes;
        uint4* agg_bf = (uint4*)p;                        p += aggb_bytes;
        int* gcnt     = (int*)p;                          p += gcnt_bytes;
        int* deg      = (int*)p;                          p += deg_bytes;
        unsigned long long* buf = (unsigned long long*)p;

        (void)hipMemsetAsync(gcnt, 0, (size_t)nbuck * sizeof(int), stream);

        int n4 = N * (FEAT / 4);
        int cblocks = (n4 + K1T - 1) / K1T;
        convert_scatter_kernel<<<nchunk + cblocks, K1T, 0, stream>>>(
            (const float4*)x, xbf, n4, sender, receiver, edge_len,
            log_scale, filter_w, filter_b, gcnt, buf, E, nbuck, cap, nchunk);
        bucket_sort_aggregate_kernel<<<nbuck, 512, 0, stream>>>(
            (const uint4*)xbf, buf, gcnt, agg_bf, deg, N, cap);
        int fblocks = (N + 63) / 64;
        finalize_kernel<<<fblocks, 256, 0, stream>>>(
            x, (const uint4*)agg_bf, deg, W_mix, out, N);
    } else {
        float* agg = (float*)d_ws;
        float* degf = agg + (size_t)N * FEAT;
        (void)hipMemsetAsync(agg, 0, ((size_t)N * FEAT + N) * sizeof(float), stream);
        int sblocks = (E * 32 + 255) / 256;
        scatter_fallback<<<sblocks, 256, 0, stream>>>(
            (const float4*)x, sender, receiver, edge_len,
            log_scale, filter_w, filter_b, agg, degf, E);
        finalize_fallback<<<512, 256, 0, stream>>>(x, agg, degf, W_mix, out, N);
    }
}